// Round 6
// baseline (272.210 us; speedup 1.0000x reference)
//
#include <hip/hip_runtime.h>
#include <hip/hip_bf16.h>
#include <math.h>

#define B 8
#define C 512
#define L 2048

using bf16x8 = __bf16 __attribute__((ext_vector_type(8)));
using f32x4  = float __attribute__((ext_vector_type(4)));

#define MFMA(a, b, c) __builtin_amdgcn_mfma_f32_16x16x32_bf16((a), (b), (c), 0, 0, 0)
// exp(v*SCALE - 12) == exp2(v*SC2 + SH2), SCALE = 1/sqrt(512)
#define SC2 0.06375872f
#define SH2 -17.312340f

// RNE f32->bf16 without NaN handling (all values here are finite)
__device__ __forceinline__ unsigned short f2bf(float f) {
    unsigned int u; __builtin_memcpy(&u, &f, 4);
    u += 0x7FFF + ((u >> 16) & 1);
    return (unsigned short)(u >> 16);
}
// async global->LDS, 16B/lane; LDS dest = wave-uniform base + lane*16
__device__ __forceinline__ void load_lds16(const unsigned short* g, unsigned short* l) {
    __builtin_amdgcn_global_load_lds(
        (const __attribute__((address_space(1))) unsigned int*)g,
        (__attribute__((address_space(3))) unsigned int*)l, 16, 0, 0);
}

// ---------------------------------------------------------------------------
// GEMM-NT core: D[128 m][128 n] = A[128][K] * B[128][K]^T (+ epilogue)
// 256 thr = 4 waves (2x2 of 64x64), BK=32, global_load_lds staging (m97).
// MODE 1: +bias[row], bf16 out      (QKV v)
// MODE 2: exp2(d*SC2+SH2) bf16 out, + row-sum atomics into ep   (scores->P)
// MODE 3: /ep[col], f32 out         (PV, ep = row sums)
// ---------------------------------------------------------------------------
template<int MODE, int KDIM>
__device__ __forceinline__ void gemm_core(
    const unsigned short* __restrict__ A,   // pre-offset to tile row m0
    const unsigned short* __restrict__ Bm,  // pre-offset to tile row n0
    unsigned short* As, unsigned short* Bs, // [128*32] each
    void* __restrict__ OutV, int ldo,       // pre-offset to (m0, n0)
    float* __restrict__ ep)                 // bias / rsum (pre-offset)
{
    const int t = threadIdx.x;
    const int wave = t >> 6, lane = t & 63;
    const int ll = t & 15, quad = (t >> 4) & 3;
    const int lr = lane >> 2, chunk = lane & 3;
    const int wm = (wave & 1) * 64, wn = (wave >> 1) * 64;

    const unsigned short* gA0 = A  + (size_t)(wave * 32 + lr) * KDIM + chunk * 8;
    const unsigned short* gB0 = Bm + (size_t)(wave * 32 + lr) * KDIM + chunk * 8;
    unsigned short* lA0 = As + (wave * 32) * 32;        // wave-uniform bases
    unsigned short* lB0 = Bs + (wave * 32) * 32;

    f32x4 acc[4][4];
#pragma unroll
    for (int i = 0; i < 4; ++i)
#pragma unroll
        for (int j = 0; j < 4; ++j) acc[i][j] = (f32x4){0.f, 0.f, 0.f, 0.f};

#pragma unroll 1
    for (int k0 = 0; k0 < KDIM; k0 += 32) {
        __syncthreads();                      // prev compute done reading LDS
        load_lds16(gA0 + k0, lA0);
        load_lds16(gA0 + (size_t)16 * KDIM + k0, lA0 + 16 * 32);
        load_lds16(gB0 + k0, lB0);
        load_lds16(gB0 + (size_t)16 * KDIM + k0, lB0 + 16 * 32);
        __syncthreads();                      // staging visible

        bf16x8 af[4], bf[4];
#pragma unroll
        for (int mi = 0; mi < 4; ++mi)
            af[mi] = *(const bf16x8*)&As[(wm + mi * 16 + ll) * 32 + quad * 8];
#pragma unroll
        for (int ni = 0; ni < 4; ++ni)
            bf[ni] = *(const bf16x8*)&Bs[(wn + ni * 16 + ll) * 32 + quad * 8];
#pragma unroll
        for (int mi = 0; mi < 4; ++mi)
#pragma unroll
            for (int ni = 0; ni < 4; ++ni)
                acc[mi][ni] = MFMA(af[mi], bf[ni], acc[mi][ni]);
    }

    float rpart[4][4];
    if (MODE == 2) {
#pragma unroll
        for (int mi = 0; mi < 4; ++mi)
#pragma unroll
            for (int r = 0; r < 4; ++r) rpart[mi][r] = 0.f;
    }

#pragma unroll
    for (int mi = 0; mi < 4; ++mi)
#pragma unroll
        for (int ni = 0; ni < 4; ++ni) {
            const int col = wn + ni * 16 + ll;
            float epc = 0.f;
            if (MODE == 3) epc = 1.0f / ep[col];
#pragma unroll
            for (int r = 0; r < 4; ++r) {
                const int row = wm + mi * 16 + quad * 4 + r;
                float v = acc[mi][ni][r];
                if (MODE == 1) v += ep[row];
                else if (MODE == 2) { v = exp2f(fmaf(v, SC2, SH2)); rpart[mi][r] += v; }
                else v *= epc;
                if (MODE == 3)
                    ((float*)OutV)[(size_t)row * ldo + col] = v;
                else
                    ((unsigned short*)OutV)[(size_t)row * ldo + col] = f2bf(v);
            }
        }

    if (MODE == 2) {   // row-sum: reduce over the 16 ll-lanes, one atomic/row
#pragma unroll
        for (int mi = 0; mi < 4; ++mi)
#pragma unroll
            for (int r = 0; r < 4; ++r) {
                float s = rpart[mi][r];
                s += __shfl_xor(s, 1, 64);
                s += __shfl_xor(s, 2, 64);
                s += __shfl_xor(s, 4, 64);
                s += __shfl_xor(s, 8, 64);
                if (ll == 0) atomicAdd(ep + wm + mi * 16 + quad * 4 + r, s);
            }
    }
}

// ---------------------------------------------------------------------------
// QK dual core: one A(xt) tile staged once, two B tiles (Wq, Wk slices),
// two 128x128 outputs. 32 MFMA / wave / k-iter.
// ---------------------------------------------------------------------------
__device__ __forceinline__ void qk_core(
    const unsigned short* __restrict__ A,
    const unsigned short* __restrict__ B0, const unsigned short* __restrict__ B1,
    unsigned short* As, unsigned short* Bs0, unsigned short* Bs1,
    unsigned short* O0, unsigned short* O1,
    const float* __restrict__ ep0, const float* __restrict__ ep1)
{
    const int t = threadIdx.x;
    const int wave = t >> 6, lane = t & 63;
    const int ll = t & 15, quad = (t >> 4) & 3;
    const int lr = lane >> 2, chunk = lane & 3;
    const int wm = (wave & 1) * 64, wn = (wave >> 1) * 64;

    const unsigned short* gA  = A  + (size_t)(wave * 32 + lr) * C + chunk * 8;
    const unsigned short* gB0 = B0 + (size_t)(wave * 32 + lr) * C + chunk * 8;
    const unsigned short* gB1 = B1 + (size_t)(wave * 32 + lr) * C + chunk * 8;
    unsigned short* lA  = As  + (wave * 32) * 32;
    unsigned short* lB0 = Bs0 + (wave * 32) * 32;
    unsigned short* lB1 = Bs1 + (wave * 32) * 32;

    f32x4 acc[2][4][4];
#pragma unroll
    for (int s = 0; s < 2; ++s)
#pragma unroll
        for (int i = 0; i < 4; ++i)
#pragma unroll
            for (int j = 0; j < 4; ++j) acc[s][i][j] = (f32x4){0.f, 0.f, 0.f, 0.f};

#pragma unroll 1
    for (int k0 = 0; k0 < C; k0 += 32) {
        __syncthreads();
        load_lds16(gA + k0, lA);
        load_lds16(gA + (size_t)16 * C + k0, lA + 16 * 32);
        load_lds16(gB0 + k0, lB0);
        load_lds16(gB0 + (size_t)16 * C + k0, lB0 + 16 * 32);
        load_lds16(gB1 + k0, lB1);
        load_lds16(gB1 + (size_t)16 * C + k0, lB1 + 16 * 32);
        __syncthreads();

        bf16x8 af[4], bq[4], bk[4];
#pragma unroll
        for (int mi = 0; mi < 4; ++mi)
            af[mi] = *(const bf16x8*)&As[(wm + mi * 16 + ll) * 32 + quad * 8];
#pragma unroll
        for (int ni = 0; ni < 4; ++ni) {
            bq[ni] = *(const bf16x8*)&Bs0[(wn + ni * 16 + ll) * 32 + quad * 8];
            bk[ni] = *(const bf16x8*)&Bs1[(wn + ni * 16 + ll) * 32 + quad * 8];
        }
#pragma unroll
        for (int mi = 0; mi < 4; ++mi)
#pragma unroll
            for (int ni = 0; ni < 4; ++ni) {
                acc[0][mi][ni] = MFMA(af[mi], bq[ni], acc[0][mi][ni]);
                acc[1][mi][ni] = MFMA(af[mi], bk[ni], acc[1][mi][ni]);
            }
    }

#pragma unroll
    for (int s = 0; s < 2; ++s) {
        unsigned short* O = s ? O1 : O0;
        const float* ep = s ? ep1 : ep0;
#pragma unroll
        for (int mi = 0; mi < 4; ++mi)
#pragma unroll
            for (int ni = 0; ni < 4; ++ni) {
                const int col = wn + ni * 16 + ll;
                const float bias = ep[col];
#pragma unroll
                for (int r = 0; r < 4; ++r) {
                    const int row = wm + mi * 16 + quad * 4 + r;
                    O[(size_t)row * C + col] = f2bf(acc[s][mi][ni][r] + bias);
                }
            }
    }
}

// ---------------------------------------------------------------------------
// Kernel 0a: x [B][C][L] fp32 -> xt [B][L][C] bf16 (64x64 tile, vectorized)
// ---------------------------------------------------------------------------
__global__ __launch_bounds__(256) void xpose_cvt(
    const float* __restrict__ x, unsigned short* __restrict__ xt)
{
    __shared__ float tile[64][69];
    const int b = blockIdx.z, l0 = blockIdx.x * 64, c0 = blockIdx.y * 64;
    const int t = threadIdx.x;
    const int lx = t & 15, cy = t >> 4;          // load: float4 along L
    const float* xb = x + (size_t)b * C * L;
#pragma unroll
    for (int p = 0; p < 4; ++p) {
        float4 v = *(const float4*)(xb + (size_t)(c0 + p * 16 + cy) * L + l0 + lx * 4);
        tile[p * 16 + cy][lx * 4 + 0] = v.x;
        tile[p * 16 + cy][lx * 4 + 1] = v.y;
        tile[p * 16 + cy][lx * 4 + 2] = v.z;
        tile[p * 16 + cy][lx * 4 + 3] = v.w;
    }
    __syncthreads();
    const int ocl = t & 15, ot = t >> 4;         // store: 4 bf16 (8B) along C
    unsigned short* xtb = xt + (size_t)b * L * C;
#pragma unroll
    for (int p = 0; p < 4; ++p) {
        int ol = p * 16 + ot;
        union { unsigned short h[4]; uint2 u; } pk;
#pragma unroll
        for (int i = 0; i < 4; ++i) pk.h[i] = f2bf(tile[ocl * 4 + i][ol]);
        *(uint2*)(xtb + (size_t)(l0 + ol) * C + c0 + ocl * 4) = pk.u;
    }
}

// ---------------------------------------------------------------------------
// Kernel 0b: Wq|Wk|Wv fp32 -> contiguous bf16; blocks 0..15 also zero rsum
// ---------------------------------------------------------------------------
__global__ __launch_bounds__(256) void wcvt(
    const float* __restrict__ Wq, const float* __restrict__ Wk,
    const float* __restrict__ Wv, unsigned short* __restrict__ o,
    float* __restrict__ rsum)
{
    if (blockIdx.x < 16) {   // zero rsum[B*L] = 16384 floats
        float4 z = make_float4(0.f, 0.f, 0.f, 0.f);
        *(float4*)(rsum + (blockIdx.x * 256 + threadIdx.x) * 4) = z;
    }
    const int i = (blockIdx.x * 256 + threadIdx.x) * 4;
    const int which = i >> 18;                            // C*C = 2^18
    const int off = i & 0x3FFFF;
    const float* src = (which == 0) ? Wq : (which == 1) ? Wk : Wv;
    float4 v = *(const float4*)(src + off);
    union { unsigned short h[4]; uint2 u; } pk;
    pk.h[0] = f2bf(v.x); pk.h[1] = f2bf(v.y); pk.h[2] = f2bf(v.z); pk.h[3] = f2bf(v.w);
    *(uint2*)(o + i) = pk.u;
}

// ---------------------------------------------------------------------------
// Kernel 1: QKV projection. 1-D grid 1024: b = id&7 (XCD), r = id>>3:
//   r <  64: QK dual block, m0 = (r&15)*128 (fastest), n0 = (r>>4)*128
//   r >= 64: V block,       m0 = (rr&3)*128,           n0 = (rr>>2)*128
// ---------------------------------------------------------------------------
__global__ __launch_bounds__(256) void qkv_gemm(
    const unsigned short* __restrict__ xt, const unsigned short* __restrict__ Wb,
    const float* __restrict__ bq, const float* __restrict__ bk,
    const float* __restrict__ bv,
    unsigned short* __restrict__ Qt, unsigned short* __restrict__ Kt,
    unsigned short* __restrict__ Vv)
{
    __shared__ unsigned short As[128 * 32], Bs0[128 * 32], Bs1[128 * 32];
    const int id = blockIdx.x;
    const int b = id & 7, r = id >> 3;          // r in 0..127
    const unsigned short* xtb = xt + (size_t)b * L * C;
    if (r < 64) {
        const int m0 = (r & 15) * 128, n0 = (r >> 4) * 128;     // M=L, N=C
        qk_core(xtb + (size_t)m0 * C,
                Wb + (size_t)n0 * C,
                Wb + (size_t)C * C + (size_t)n0 * C,
                As, Bs0, Bs1,
                Qt + (size_t)b * L * C + (size_t)m0 * C + n0,
                Kt + (size_t)b * L * C + (size_t)m0 * C + n0,
                bq + n0, bk + n0);
    } else {
        const int rr = r - 64;
        const int m0 = (rr & 3) * 128, n0 = (rr >> 2) * 128;    // M=C, N=L
        const unsigned short* A  = Wb + (size_t)2 * C * C + (size_t)m0 * C;
        const unsigned short* Bm = xtb + (size_t)n0 * C;
        unsigned short* Out = Vv + (size_t)b * C * L + (size_t)m0 * L + n0;
        gemm_core<1, C>(A, Bm, As, Bs0, Out, L, const_cast<float*>(bv + m0));
    }
}

// ---------------------------------------------------------------------------
// Kernel 2: P = exp(Q K^T * scale - 12) + fused row-sum atomics
// 1-D grid: b = id&7 (XCD), r = id>>3, m = r & (mtiles-1) fastest, n = rest
// ---------------------------------------------------------------------------
__global__ __launch_bounds__(256) void sc_exp(
    const unsigned short* __restrict__ Qt, const unsigned short* __restrict__ Kt,
    unsigned short* __restrict__ P, float* __restrict__ rsum,
    int hoff, int qrows, int mshift)
{
    __shared__ unsigned short As[128 * 32], Bs[128 * 32];
    const int id = blockIdx.x;
    const int b = id & 7, r = id >> 3;
    const int m0 = (r & ((1 << mshift) - 1)) * 128, n0 = (r >> mshift) * 128;
    const unsigned short* A  = Qt + (size_t)b * L * C + (size_t)(hoff + m0) * C;
    const unsigned short* Bm = Kt + (size_t)b * L * C + (size_t)n0 * C;
    unsigned short* Out = P + (size_t)b * qrows * L + (size_t)m0 * L + n0;
    float* ep = rsum + (size_t)b * L + hoff + m0;
    gemm_core<2, C>(A, Bm, As, Bs, Out, L, ep);
}

// ---------------------------------------------------------------------------
// Kernel 3: O = (V @ P^T) / rsum[col]
// 1-D grid: b = id&7 (XCD), r = id>>3, m = r&3 fastest (M=C: 4 tiles), n rest
// ---------------------------------------------------------------------------
__global__ __launch_bounds__(256) void pv_gemm(
    const unsigned short* __restrict__ Vv, const unsigned short* __restrict__ P,
    const float* __restrict__ rsum, float* __restrict__ out,
    int hoff, int qrows)
{
    __shared__ unsigned short As[128 * 32], Bs[128 * 32];
    const int id = blockIdx.x;
    const int b = id & 7, r = id >> 3;
    const int m0 = (r & 3) * 128, n0 = (r >> 2) * 128;
    const unsigned short* A  = Vv + (size_t)b * C * L + (size_t)m0 * L;
    const unsigned short* Bm = P + (size_t)b * qrows * L + (size_t)n0 * L;
    float* Out = out + (size_t)b * C * L + (size_t)m0 * L + hoff + n0;
    float* ep = const_cast<float*>(rsum) + (size_t)b * L + hoff + n0;
    gemm_core<3, L>(A, Bm, As, Bs, Out, L, ep);
}

extern "C" void kernel_launch(void* const* d_in, const int* in_sizes, int n_in,
                              void* d_out, int out_size, void* d_ws, size_t ws_size,
                              hipStream_t stream) {
    const float* x  = (const float*)d_in[0];
    const float* Wq = (const float*)d_in[1];
    const float* bq = (const float*)d_in[2];
    const float* Wk = (const float*)d_in[3];
    const float* bk = (const float*)d_in[4];
    const float* Wv = (const float*)d_in[5];
    const float* bv = (const float*)d_in[6];
    float* out = (float*)d_out;

    const size_t BCL = (size_t)B * C * L;                // 8.39M elems
    const bool fullP = ws_size >= 119078912ull;          // full-P footprint

    unsigned short* Qt = (unsigned short*)d_ws;          // [B][L][C] bf16
    unsigned short* Kt = Qt + BCL;
    unsigned short* Vv = Kt + BCL;                       // [B][C][L]
    unsigned short *Wb, *xt, *P;
    float* rsum;
    if (fullP) {
        Wb   = Vv + BCL;                                 // 1.57 MB, live during qkv
        rsum = (float*)(Wb + (size_t)3 * C * C);         // [B][L] f32
        xt   = (unsigned short*)(rsum + (size_t)B * L);  // dead after qkv
        P    = xt;                                       // [B][L][L] bf16, aliases xt
    } else {                                             // 85.6 MB fallback
        xt   = Vv + BCL;
        P    = xt;                                       // [B][1024][L], aliases xt
        Wb   = P + (size_t)B * 1024 * L;
        rsum = (float*)(Wb + (size_t)3 * C * C);
    }

    xpose_cvt<<<dim3(L / 64, C / 64, B), 256, 0, stream>>>(x, xt);
    wcvt<<<dim3(3 * C * C / 1024), 256, 0, stream>>>(Wq, Wk, Wv, Wb, rsum);
    qkv_gemm<<<dim3(1024), 256, 0, stream>>>(xt, Wb, bq, bk, bv, Qt, Kt, Vv);

    if (fullP) {
        sc_exp<<<dim3(2048), 256, 0, stream>>>(Qt, Kt, P, rsum, 0, L, 4);
        pv_gemm<<<dim3(512), 256, 0, stream>>>(Vv, P, rsum, out, 0, L);
    } else {
        for (int h = 0; h < 2; ++h) {
            sc_exp<<<dim3(1024), 256, 0, stream>>>(Qt, Kt, P, rsum, h * 1024, 1024, 3);
            pv_gemm<<<dim3(256), 256, 0, stream>>>(Vv, P, rsum, out, h * 1024, 1024);
        }
    }
}

// Round 7
// 231.285 us; speedup vs baseline: 1.1769x; 1.1769x over previous
//
#include <hip/hip_runtime.h>
#include <hip/hip_bf16.h>
#include <math.h>

#define B 8
#define C 512
#define L 2048

using bf16x8 = __bf16 __attribute__((ext_vector_type(8)));
using f32x4  = float __attribute__((ext_vector_type(4)));

#define MFMA(a, b, c) __builtin_amdgcn_mfma_f32_16x16x32_bf16((a), (b), (c), 0, 0, 0)
// exp(v*SCALE - 12) == exp2(v*SC2 + SH2), SCALE = 1/sqrt(512)
#define SC2 0.06375872f
#define SH2 -17.312340f

// RNE f32->bf16 without NaN handling (all values here are finite)
__device__ __forceinline__ unsigned short f2bf(float f) {
    unsigned int u; __builtin_memcpy(&u, &f, 4);
    u += 0x7FFF + ((u >> 16) & 1);
    return (unsigned short)(u >> 16);
}
// async global->LDS, 16B/lane; LDS dest = wave-uniform base + lane*16
__device__ __forceinline__ void load_lds16(const unsigned short* g, unsigned short* l) {
    __builtin_amdgcn_global_load_lds(
        (const __attribute__((address_space(1))) unsigned int*)g,
        (__attribute__((address_space(3))) unsigned int*)l, 16, 0, 0);
}

// ---------------------------------------------------------------------------
// GEMM-NT core: D[128 m][128 n] = A[128][K] * B[128][K]^T (+ epilogue)
// 256 thr = 4 waves (2x2 of 64x64). BK=64 as two BK=32 panels staged per
// barrier pair (halves barrier-drain count vs m97; same LDS row layout).
// As/Bs each hold 2 panels of 128x32 bf16 (16 KB) -> 32 KB total.
// MODE 0: +bias[col], bf16 out      (QKV q/k)
// MODE 1: +bias[row], bf16 out      (QKV v)
// MODE 2: exp2(d*SC2+SH2) bf16 out, + row-sum atomics into ep   (scores->P)
// MODE 3: /ep[col], f32 out         (PV, ep = row sums)
// ---------------------------------------------------------------------------
template<int MODE, int KDIM>
__device__ __forceinline__ void gemm_core(
    const unsigned short* __restrict__ A,   // pre-offset to tile row m0
    const unsigned short* __restrict__ Bm,  // pre-offset to tile row n0
    unsigned short* As, unsigned short* Bs, // [2][128*32] each
    void* __restrict__ OutV, int ldo,       // pre-offset to (m0, n0)
    float* __restrict__ ep)                 // bias / rsum (pre-offset)
{
    const int t = threadIdx.x;
    const int wave = t >> 6, lane = t & 63;
    const int ll = t & 15, quad = (t >> 4) & 3;
    const int lr = lane >> 2, chunk = lane & 3;
    const int wm = (wave & 1) * 64, wn = (wave >> 1) * 64;

    const unsigned short* gA0 = A  + (size_t)(wave * 32 + lr) * KDIM + chunk * 8;
    const unsigned short* gB0 = Bm + (size_t)(wave * 32 + lr) * KDIM + chunk * 8;
    unsigned short* lA0 = As + (wave * 32) * 32;        // wave-uniform bases
    unsigned short* lB0 = Bs + (wave * 32) * 32;
    const int P1 = 128 * 32;                            // panel-1 offset

    f32x4 acc[4][4];
#pragma unroll
    for (int i = 0; i < 4; ++i)
#pragma unroll
        for (int j = 0; j < 4; ++j) acc[i][j] = (f32x4){0.f, 0.f, 0.f, 0.f};

#pragma unroll 1
    for (int k0 = 0; k0 < KDIM; k0 += 64) {
        __syncthreads();                      // prev compute done reading LDS
        load_lds16(gA0 + k0, lA0);
        load_lds16(gA0 + (size_t)16 * KDIM + k0, lA0 + 16 * 32);
        load_lds16(gA0 + k0 + 32, lA0 + P1);
        load_lds16(gA0 + (size_t)16 * KDIM + k0 + 32, lA0 + P1 + 16 * 32);
        load_lds16(gB0 + k0, lB0);
        load_lds16(gB0 + (size_t)16 * KDIM + k0, lB0 + 16 * 32);
        load_lds16(gB0 + k0 + 32, lB0 + P1);
        load_lds16(gB0 + (size_t)16 * KDIM + k0 + 32, lB0 + P1 + 16 * 32);
        __syncthreads();                      // staging visible

#pragma unroll
        for (int p = 0; p < 2; ++p) {
            bf16x8 af[4], bf[4];
#pragma unroll
            for (int mi = 0; mi < 4; ++mi)
                af[mi] = *(const bf16x8*)&As[p * P1 + (wm + mi * 16 + ll) * 32 + quad * 8];
#pragma unroll
            for (int ni = 0; ni < 4; ++ni)
                bf[ni] = *(const bf16x8*)&Bs[p * P1 + (wn + ni * 16 + ll) * 32 + quad * 8];
#pragma unroll
            for (int mi = 0; mi < 4; ++mi)
#pragma unroll
                for (int ni = 0; ni < 4; ++ni)
                    acc[mi][ni] = MFMA(af[mi], bf[ni], acc[mi][ni]);
        }
    }

    float rpart[4][4];
    if (MODE == 2) {
#pragma unroll
        for (int mi = 0; mi < 4; ++mi)
#pragma unroll
            for (int r = 0; r < 4; ++r) rpart[mi][r] = 0.f;
    }

#pragma unroll
    for (int mi = 0; mi < 4; ++mi)
#pragma unroll
        for (int ni = 0; ni < 4; ++ni) {
            const int col = wn + ni * 16 + ll;
            float epc = 0.f;
            if (MODE == 0) epc = ep[col];
            if (MODE == 3) epc = 1.0f / ep[col];
#pragma unroll
            for (int r = 0; r < 4; ++r) {
                const int row = wm + mi * 16 + quad * 4 + r;
                float v = acc[mi][ni][r];
                if (MODE == 0)      v += epc;
                else if (MODE == 1) v += ep[row];
                else if (MODE == 2) { v = exp2f(fmaf(v, SC2, SH2)); rpart[mi][r] += v; }
                else                v *= epc;
                if (MODE == 3)
                    ((float*)OutV)[(size_t)row * ldo + col] = v;
                else
                    ((unsigned short*)OutV)[(size_t)row * ldo + col] = f2bf(v);
            }
        }

    if (MODE == 2) {   // row-sum: reduce over the 16 ll-lanes, one atomic/row
#pragma unroll
        for (int mi = 0; mi < 4; ++mi)
#pragma unroll
            for (int r = 0; r < 4; ++r) {
                float s = rpart[mi][r];
                s += __shfl_xor(s, 1, 64);
                s += __shfl_xor(s, 2, 64);
                s += __shfl_xor(s, 4, 64);
                s += __shfl_xor(s, 8, 64);
                if (ll == 0) atomicAdd(ep + wm + mi * 16 + quad * 4 + r, s);
            }
    }
}

// ---------------------------------------------------------------------------
// Kernel 0a: x [B][C][L] fp32 -> xt [B][L][C] bf16 (64x64 tile, vectorized)
// ---------------------------------------------------------------------------
__global__ __launch_bounds__(256) void xpose_cvt(
    const float* __restrict__ x, unsigned short* __restrict__ xt)
{
    __shared__ float tile[64][69];
    const int b = blockIdx.z, l0 = blockIdx.x * 64, c0 = blockIdx.y * 64;
    const int t = threadIdx.x;
    const int lx = t & 15, cy = t >> 4;          // load: float4 along L
    const float* xb = x + (size_t)b * C * L;
#pragma unroll
    for (int p = 0; p < 4; ++p) {
        float4 v = *(const float4*)(xb + (size_t)(c0 + p * 16 + cy) * L + l0 + lx * 4);
        tile[p * 16 + cy][lx * 4 + 0] = v.x;
        tile[p * 16 + cy][lx * 4 + 1] = v.y;
        tile[p * 16 + cy][lx * 4 + 2] = v.z;
        tile[p * 16 + cy][lx * 4 + 3] = v.w;
    }
    __syncthreads();
    const int ocl = t & 15, ot = t >> 4;         // store: 4 bf16 (8B) along C
    unsigned short* xtb = xt + (size_t)b * L * C;
#pragma unroll
    for (int p = 0; p < 4; ++p) {
        int ol = p * 16 + ot;
        union { unsigned short h[4]; uint2 u; } pk;
#pragma unroll
        for (int i = 0; i < 4; ++i) pk.h[i] = f2bf(tile[ocl * 4 + i][ol]);
        *(uint2*)(xtb + (size_t)(l0 + ol) * C + c0 + ocl * 4) = pk.u;
    }
}

// ---------------------------------------------------------------------------
// Kernel 0b: Wq|Wk|Wv fp32 -> contiguous bf16; blocks 0..15 also zero rsum
// ---------------------------------------------------------------------------
__global__ __launch_bounds__(256) void wcvt(
    const float* __restrict__ Wq, const float* __restrict__ Wk,
    const float* __restrict__ Wv, unsigned short* __restrict__ o,
    float* __restrict__ rsum)
{
    if (blockIdx.x < 16) {   // zero rsum[B*L] = 16384 floats
        float4 z = make_float4(0.f, 0.f, 0.f, 0.f);
        *(float4*)(rsum + (blockIdx.x * 256 + threadIdx.x) * 4) = z;
    }
    const int i = (blockIdx.x * 256 + threadIdx.x) * 4;
    const int which = i >> 18;                            // C*C = 2^18
    const int off = i & 0x3FFFF;
    const float* src = (which == 0) ? Wq : (which == 1) ? Wk : Wv;
    float4 v = *(const float4*)(src + off);
    union { unsigned short h[4]; uint2 u; } pk;
    pk.h[0] = f2bf(v.x); pk.h[1] = f2bf(v.y); pk.h[2] = f2bf(v.z); pk.h[3] = f2bf(v.w);
    *(uint2*)(o + i) = pk.u;
}

// ---------------------------------------------------------------------------
// Kernel 1: QKV projection. 1-D grid 1536: b = id&7 (XCD), r = id>>3:
//   which = r>>6; q/k: m = tt&15 (fastest), n = tt>>4; v: m = tt&3, n = tt>>2
// ---------------------------------------------------------------------------
__global__ __launch_bounds__(256) void qkv_gemm(
    const unsigned short* __restrict__ xt, const unsigned short* __restrict__ Wb,
    const float* __restrict__ bq, const float* __restrict__ bk,
    const float* __restrict__ bv,
    unsigned short* __restrict__ Qt, unsigned short* __restrict__ Kt,
    unsigned short* __restrict__ Vv)
{
    __shared__ unsigned short As[2 * 128 * 32], Bs[2 * 128 * 32];
    const int id = blockIdx.x;
    const int b = id & 7, r = id >> 3;          // r in 0..191
    const int which = r >> 6, tt = r & 63;
    const unsigned short* xtb = xt + (size_t)b * L * C;
    if (which < 2) {
        const int m0 = (tt & 15) * 128, n0 = (tt >> 4) * 128;   // M=L, N=C
        const unsigned short* A  = xtb + (size_t)m0 * C;
        const unsigned short* Bm = Wb + (size_t)which * C * C + (size_t)n0 * C;
        unsigned short* Out = (which ? Kt : Qt) + (size_t)b * L * C
                              + (size_t)m0 * C + n0;
        gemm_core<0, C>(A, Bm, As, Bs, Out, C,
                        const_cast<float*>((which ? bk : bq) + n0));
    } else {
        const int m0 = (tt & 3) * 128, n0 = (tt >> 2) * 128;    // M=C, N=L
        const unsigned short* A  = Wb + (size_t)2 * C * C + (size_t)m0 * C;
        const unsigned short* Bm = xtb + (size_t)n0 * C;
        unsigned short* Out = Vv + (size_t)b * C * L + (size_t)m0 * L + n0;
        gemm_core<1, C>(A, Bm, As, Bs, Out, L, const_cast<float*>(bv + m0));
    }
}

// ---------------------------------------------------------------------------
// Kernel 2: P = exp(Q K^T * scale - 12) + fused row-sum atomics
// 1-D grid: b = id&7 (XCD), r = id>>3, m = r & (mtiles-1) fastest, n = rest
// ---------------------------------------------------------------------------
__global__ __launch_bounds__(256) void sc_exp(
    const unsigned short* __restrict__ Qt, const unsigned short* __restrict__ Kt,
    unsigned short* __restrict__ P, float* __restrict__ rsum,
    int hoff, int qrows, int mshift)
{
    __shared__ unsigned short As[2 * 128 * 32], Bs[2 * 128 * 32];
    const int id = blockIdx.x;
    const int b = id & 7, r = id >> 3;
    const int m0 = (r & ((1 << mshift) - 1)) * 128, n0 = (r >> mshift) * 128;
    const unsigned short* A  = Qt + (size_t)b * L * C + (size_t)(hoff + m0) * C;
    const unsigned short* Bm = Kt + (size_t)b * L * C + (size_t)n0 * C;
    unsigned short* Out = P + (size_t)b * qrows * L + (size_t)m0 * L + n0;
    float* ep = rsum + (size_t)b * L + hoff + m0;
    gemm_core<2, C>(A, Bm, As, Bs, Out, L, ep);
}

// ---------------------------------------------------------------------------
// Kernel 3: O = (V @ P^T) / rsum[col]
// 1-D grid: b = id&7 (XCD), r = id>>3, m = r&3 fastest (M=C: 4 tiles), n rest
// ---------------------------------------------------------------------------
__global__ __launch_bounds__(256) void pv_gemm(
    const unsigned short* __restrict__ Vv, const unsigned short* __restrict__ P,
    const float* __restrict__ rsum, float* __restrict__ out,
    int hoff, int qrows)
{
    __shared__ unsigned short As[2 * 128 * 32], Bs[2 * 128 * 32];
    const int id = blockIdx.x;
    const int b = id & 7, r = id >> 3;
    const int m0 = (r & 3) * 128, n0 = (r >> 2) * 128;
    const unsigned short* A  = Vv + (size_t)b * C * L + (size_t)m0 * L;
    const unsigned short* Bm = P + (size_t)b * qrows * L + (size_t)n0 * L;
    float* Out = out + (size_t)b * C * L + (size_t)m0 * L + hoff + n0;
    float* ep = const_cast<float*>(rsum) + (size_t)b * L + hoff + n0;
    gemm_core<3, L>(A, Bm, As, Bs, Out, L, ep);
}

extern "C" void kernel_launch(void* const* d_in, const int* in_sizes, int n_in,
                              void* d_out, int out_size, void* d_ws, size_t ws_size,
                              hipStream_t stream) {
    const float* x  = (const float*)d_in[0];
    const float* Wq = (const float*)d_in[1];
    const float* bq = (const float*)d_in[2];
    const float* Wk = (const float*)d_in[3];
    const float* bk = (const float*)d_in[4];
    const float* Wv = (const float*)d_in[5];
    const float* bv = (const float*)d_in[6];
    float* out = (float*)d_out;

    const size_t BCL = (size_t)B * C * L;                // 8.39M elems
    const bool fullP = ws_size >= 119078912ull;          // full-P footprint

    unsigned short* Qt = (unsigned short*)d_ws;          // [B][L][C] bf16
    unsigned short* Kt = Qt + BCL;
    unsigned short* Vv = Kt + BCL;                       // [B][C][L]
    unsigned short *Wb, *xt, *P;
    float* rsum;
    if (fullP) {
        Wb   = Vv + BCL;                                 // 1.57 MB, live during qkv
        rsum = (float*)(Wb + (size_t)3 * C * C);         // [B][L] f32
        xt   = (unsigned short*)(rsum + (size_t)B * L);  // dead after qkv
        P    = xt;                                       // [B][L][L] bf16, aliases xt
    } else {                                             // 85.6 MB fallback
        xt   = Vv + BCL;
        P    = xt;                                       // [B][1024][L], aliases xt
        Wb   = P + (size_t)B * 1024 * L;
        rsum = (float*)(Wb + (size_t)3 * C * C);
    }

    xpose_cvt<<<dim3(L / 64, C / 64, B), 256, 0, stream>>>(x, xt);
    wcvt<<<dim3(3 * C * C / 1024), 256, 0, stream>>>(Wq, Wk, Wv, Wb, rsum);
    qkv_gemm<<<dim3(1536), 256, 0, stream>>>(xt, Wb, bq, bk, bv, Qt, Kt, Vv);

    if (fullP) {
        sc_exp<<<dim3(2048), 256, 0, stream>>>(Qt, Kt, P, rsum, 0, L, 4);
        pv_gemm<<<dim3(512), 256, 0, stream>>>(Vv, P, rsum, out, 0, L);
    } else {
        for (int h = 0; h < 2; ++h) {
            sc_exp<<<dim3(1024), 256, 0, stream>>>(Qt, Kt, P, rsum, h * 1024, 1024, 3);
            pv_gemm<<<dim3(256), 256, 0, stream>>>(Vv, P, rsum, out, h * 1024, 1024);
        }
    }
}